// Round 15
// baseline (6102.773 us; speedup 1.0000x reference)
//
#include <hip/hip_runtime.h>
#include <math.h>

#define NITER 1000
#define LRATE 0.1f
#define KLOG 0.10213724040f            // (2/512)*(20/ln10)*ln10/ln2/... = alpha*10*log10(2)^-1 folded
#define IINIT_SCALE -0.332192809488736f  // -(alpha/KLOG) = -log2(10)/10

typedef unsigned int v2u __attribute__((ext_vector_type(2)));

__device__ __forceinline__ float rcpf(float x) { return __builtin_amdgcn_rcpf(x); }

__device__ __forceinline__ float readlane_f(float v, int l) {
    return __int_as_float(__builtin_amdgcn_readlane(__float_as_int(v), l));
}

template<int CTRL>
__device__ __forceinline__ float dpp_mov(float v) {
    return __int_as_float(__builtin_amdgcn_update_dpp(0, __float_as_int(v), CTRL, 0xF, 0xF, true));
}

__device__ __forceinline__ int lane_id() {
    return __builtin_amdgcn_mbcnt_hi(~0u, __builtin_amdgcn_mbcnt_lo(~0u, 0u));
}

__device__ __forceinline__ void swap16(float& x, float& y) {
#if __has_builtin(__builtin_amdgcn_permlane16_swap)
    v2u r = __builtin_amdgcn_permlane16_swap(__float_as_uint(x), __float_as_uint(y), false, false);
    x = __uint_as_float(r[0]);
    y = __uint_as_float(r[1]);
#else
    const bool up = lane_id() & 16;
    const float send = up ? x : y;
    const float recv = __shfl_xor(send, 16);
    x = up ? recv : x;
    y = up ? y : recv;
#endif
}

__device__ __forceinline__ void swap32(float& x, float& y) {
#if __has_builtin(__builtin_amdgcn_permlane32_swap)
    v2u r = __builtin_amdgcn_permlane32_swap(__float_as_uint(x), __float_as_uint(y), false, false);
    x = __uint_as_float(r[0]);
    y = __uint_as_float(r[1]);
#else
    const bool up = lane_id() & 32;
    const float send = up ? x : y;
    const float recv = __shfl_xor(send, 32);
    x = up ? recv : x;
    y = up ? y : recv;
#endif
}

// One block, 512 threads = 8 waves (2/SIMD). Wave w owns sections {2w,2w+1}
// (A,B), 12 wave-uniform coefficient scalars. Lane L owns freqs 8L..8L+7.
//
// NO K-pass phase: the cross-section product is accumulated in LOG domain via
// ds_add_f32 into Kacc[cur][9L+f] (stride 9 is coprime to 32 banks -> 2-way
// alias = free for both atomics and reads). Double-buffered: phase C of iter
// k re-initializes buffer k+1 with IINIT (= -log2(10)/10 * target, so that
// K = KLOG * Kacc_final); barriers separate init/add/read hazards:
//   A: adds -> Kacc[cur]            (inits of cur written before prev bar2)
//   bar1
//   C: reads Kacc[cur]; writes init -> Kacc[cur^1]; moments/update
//   bar2
// Gradients via moment sums (R12-verified machinery, absmax 0.0).
__global__ __launch_bounds__(512, 1)
void sgd_filter_design_kernel(const float* __restrict__ target,
                              const float* __restrict__ sos_init,
                              float* __restrict__ out)
{
    const int t = threadIdx.x;
    const int w = t >> 6;
    const int L = t & 63;

    __shared__ float Kacc[2][576];

    // per-freq cosine constants
    const float PI = 3.14159265358979323846f;
    float C1[8], C2[8];
    #pragma unroll
    for (int f = 0; f < 8; ++f) {
        const int n = 8 * L + f;
        const float wr = PI * (float)n / 511.0f;
        const float c1 = cosf(wr);
        C1[f] = c1;
        C2[f] = 2.0f * c1 * c1 - 1.0f;
    }

    // init value for freq t (-alpha*tgt folded into the log accumulator)
    const float Iinit = IINIT_SCALE * target[t];
    const int kinit = 9 * (t >> 3) + (t & 7);
    Kacc[0][kinit] = Iinit;

    const int kbase = 9 * L;    // this lane's accumulator base (freqs 8L..8L+7)

    // butterfly: 16 columns, level masks [16,32,1,2], weights [8,4,2,1]
    const int col = ((L & 16) >> 1) | ((L & 32) >> 3) | ((L & 1) << 1) | ((L & 2) >> 1);
    const bool up1 = L & 1, up2 = L & 2;

    // init 12 wave-uniform coefs; col c lives at lane 16*c3 + 32*c2 + c1 + 2*c0
    float v0 = 0.0f;
    if (col < 12) v0 = sos_init[12 * w + col];
    float b0A = readlane_f(v0, 0);
    float b1A = readlane_f(v0, 2);
    float b2A = readlane_f(v0, 1);
    float a0A = readlane_f(v0, 3);
    float a1A = readlane_f(v0, 32);
    float a2A = readlane_f(v0, 34);
    float b0B = readlane_f(v0, 33);
    float b1B = readlane_f(v0, 35);
    float b2B = readlane_f(v0, 16);
    float a0B = readlane_f(v0, 18);
    float a1B = readlane_f(v0, 17);
    float a2B = readlane_f(v0, 19);

    __syncthreads();

    int cur = 0;
    for (int it = 0; it < NITER; ++it) {
        // ---- wave-uniform polynomial coefficients (x2 folded, exact) ----
        const float PA0 = fmaf(b0A, b0A, fmaf(b1A, b1A, b2A * b2A));
        float PA1 = b1A * (b0A + b2A); PA1 += PA1;
        float PA2 = b0A * b2A;         PA2 += PA2;
        const float QA0 = fmaf(a0A, a0A, fmaf(a1A, a1A, a2A * a2A));
        float QA1 = a1A * (a0A + a2A); QA1 += QA1;
        float QA2 = a0A * a2A;         QA2 += QA2;
        const float PB0 = fmaf(b0B, b0B, fmaf(b1B, b1B, b2B * b2B));
        float PB1 = b1B * (b0B + b2B); PB1 += PB1;
        float PB2 = b0B * b2B;         PB2 += PB2;
        const float QB0 = fmaf(a0B, a0B, fmaf(a1B, a1B, a2B * a2B));
        float QB1 = a1B * (a0B + a2B); QB1 += QB1;
        float QB2 = a0B * a2B;         QB2 += QB2;

        // ---- phase A: forward, 2 sections x 8 freqs; log-atomic publish ----
        float imnA[8], imdA[8], imnB[8], imdB[8];
        #pragma unroll
        for (int f = 0; f < 8; ++f) {
            float mnA = fmaf(PA2, C2[f], fmaf(PA1, C1[f], PA0));
            float mdA = fmaf(QA2, C2[f], fmaf(QA1, C1[f], QA0));
            float mnB = fmaf(PB2, C2[f], fmaf(PB1, C1[f], PB0));
            float mdB = fmaf(QB2, C2[f], fmaf(QB1, C1[f], QB0));
            mnA = fmaxf(mnA, 1e-18f);   // guard: poly can round negative
            mdA = fmaxf(mdA, 1e-18f);
            mnB = fmaxf(mnB, 1e-18f);
            mdB = fmaxf(mdB, 1e-18f);
            const float rA = rcpf(mnA * mdA);
            const float rB = rcpf(mnB * mdB);
            imnA[f] = rA * mdA; imdA[f] = rA * mnA;
            imnB[f] = rB * mdB; imdB[f] = rB * mnB;
            const float qAB = (mnA * imdA[f]) * (mnB * imdB[f]);
            atomicAdd(&Kacc[cur][kbase + f], __log2f(qAB));
        }
        __syncthreads();   // bar1: all log-contributions accumulated

        // ---- phase C: read K, re-init other buffer, moments, update ----
        float Kf[8];
        #pragma unroll
        for (int f = 0; f < 8; ++f) Kf[f] = KLOG * Kacc[cur][kbase + f];
        Kacc[cur ^ 1][kinit] = Iinit;     // init next iter's buffer

        float SA0, SA1, SA2, TA0, TA1, TA2;
        float SB0, SB1, SB2, TB0, TB1, TB2;
        #pragma unroll
        for (int f = 0; f < 8; ++f) {
            const float EA = Kf[f] * imnA[f];
            const float FA = Kf[f] * imdA[f];
            const float EB = Kf[f] * imnB[f];
            const float FB = Kf[f] * imdB[f];
            if (f == 0) {
                SA0 = EA;          TA0 = FA;
                SA1 = EA * C1[f];  TA1 = FA * C1[f];
                SA2 = EA * C2[f];  TA2 = FA * C2[f];
                SB0 = EB;          TB0 = FB;
                SB1 = EB * C1[f];  TB1 = FB * C1[f];
                SB2 = EB * C2[f];  TB2 = FB * C2[f];
            } else {
                SA0 += EA;                    TA0 += FA;
                SA1 = fmaf(EA, C1[f], SA1);   TA1 = fmaf(FA, C1[f], TA1);
                SA2 = fmaf(EA, C2[f], SA2);   TA2 = fmaf(FA, C2[f], TA2);
                SB0 += EB;                    TB0 += FB;
                SB1 = fmaf(EB, C1[f], SB1);   TB1 = fmaf(FB, C1[f], TB1);
                SB2 = fmaf(EB, C2[f], SB2);   TB2 = fmaf(FB, C2[f], TB2);
            }
        }
        const float g12[12] = {SA0, SA1, SA2, TA0, TA1, TA2,
                               SB0, SB1, SB2, TB0, TB1, TB2};

        // ---- butterfly reduce-scatter: 16 cols (12 real + 4 pad) ----
        float r8v[8];
        #pragma unroll
        for (int i = 0; i < 8; ++i) {            // mask 16, weight 8
            float x = g12[i];
            float y = (i + 8 < 12) ? g12[i + 8] : 0.0f;
            swap16(x, y);
            r8v[i] = x + y;
        }
        float r4v[4];
        #pragma unroll
        for (int i = 0; i < 4; ++i) {            // mask 32, weight 4
            float x = r8v[i], y = r8v[i + 4];
            swap32(x, y);
            r4v[i] = x + y;
        }
        float r2v[2];
        #pragma unroll
        for (int i = 0; i < 2; ++i) {            // mask 1 (DPP), weight 2
            const float x = r4v[i], y = r4v[i + 2];
            const float P = up1 ? y : x, Q = up1 ? x : y;
            r2v[i] = P + dpp_mov<0xB1>(Q);
        }
        float r1v;
        {                                         // mask 2 (DPP), weight 1
            const float x = r2v[0], y = r2v[1];
            const float P = up2 ? y : x, Q = up2 ? x : y;
            r1v = P + dpp_mov<0x4E>(Q);
        }
        r1v += dpp_mov<0x128>(r1v);               // mask 8 full sum
        r1v += __shfl_xor(r1v, 4);                // mask 4 full sum

        // ---- extract the 12 moment sums (wave-uniform) ----
        const float sSA0 = readlane_f(r1v, 0);
        const float sSA1 = readlane_f(r1v, 2);
        const float sSA2 = readlane_f(r1v, 1);
        const float sTA0 = readlane_f(r1v, 3);
        const float sTA1 = readlane_f(r1v, 32);
        const float sTA2 = readlane_f(r1v, 34);
        const float sSB0 = readlane_f(r1v, 33);
        const float sSB1 = readlane_f(r1v, 35);
        const float sSB2 = readlane_f(r1v, 16);
        const float sTB0 = readlane_f(r1v, 18);
        const float sTB1 = readlane_f(r1v, 17);
        const float sTB2 = readlane_f(r1v, 19);

        // ---- rebuild gradients and update (b-side -=, a-side +=) ----
        const float gb0A = fmaf(b0A, sSA0, fmaf(b1A, sSA1, b2A * sSA2));
        const float gb1A = fmaf(b0A + b2A, sSA1, b1A * sSA0);
        const float gb2A = fmaf(b0A, sSA2, fmaf(b1A, sSA1, b2A * sSA0));
        const float ga0A = fmaf(a0A, sTA0, fmaf(a1A, sTA1, a2A * sTA2));
        const float ga1A = fmaf(a0A + a2A, sTA1, a1A * sTA0);
        const float ga2A = fmaf(a0A, sTA2, fmaf(a1A, sTA1, a2A * sTA0));
        const float gb0B = fmaf(b0B, sSB0, fmaf(b1B, sSB1, b2B * sSB2));
        const float gb1B = fmaf(b0B + b2B, sSB1, b1B * sSB0);
        const float gb2B = fmaf(b0B, sSB2, fmaf(b1B, sSB1, b2B * sSB0));
        const float ga0B = fmaf(a0B, sTB0, fmaf(a1B, sTB1, a2B * sTB2));
        const float ga1B = fmaf(a0B + a2B, sTB1, a1B * sTB0);
        const float ga2B = fmaf(a0B, sTB2, fmaf(a1B, sTB1, a2B * sTB0));

        b0A = fmaf(-LRATE, gb0A, b0A);
        b1A = fmaf(-LRATE, gb1A, b1A);
        b2A = fmaf(-LRATE, gb2A, b2A);
        a0A = fmaf( LRATE, ga0A, a0A);
        a1A = fmaf( LRATE, ga1A, a1A);
        a2A = fmaf( LRATE, ga2A, a2A);
        b0B = fmaf(-LRATE, gb0B, b0B);
        b1B = fmaf(-LRATE, gb1B, b1B);
        b2B = fmaf(-LRATE, gb2B, b2B);
        a0B = fmaf( LRATE, ga0B, a0B);
        a1B = fmaf( LRATE, ga1B, a1B);
        a2B = fmaf( LRATE, ga2B, a2B);

        __syncthreads();   // bar2: next iter's atomics may not start before
                           // this iter's reads+inits complete
        cur ^= 1;
    }

    if (L == 0) {
        out[12 * w + 0]  = b0A;
        out[12 * w + 1]  = b1A;
        out[12 * w + 2]  = b2A;
        out[12 * w + 3]  = a0A;
        out[12 * w + 4]  = a1A;
        out[12 * w + 5]  = a2A;
        out[12 * w + 6]  = b0B;
        out[12 * w + 7]  = b1B;
        out[12 * w + 8]  = b2B;
        out[12 * w + 9]  = a0B;
        out[12 * w + 10] = a1B;
        out[12 * w + 11] = a2B;
    }
}

extern "C" void kernel_launch(void* const* d_in, const int* in_sizes, int n_in,
                              void* d_out, int out_size, void* d_ws, size_t ws_size,
                              hipStream_t stream) {
    const float* target   = (const float*)d_in[0];   // (512,)
    const float* sos_init = (const float*)d_in[1];   // (1,16,6) = 96
    float* out = (float*)d_out;                      // 96 floats
    hipLaunchKernelGGL(sgd_filter_design_kernel, dim3(1), dim3(512), 0, stream,
                       target, sos_init, out);
}

// Round 16
// 1859.535 us; speedup vs baseline: 3.2819x; 3.2819x over previous
//
#include <hip/hip_runtime.h>
#include <math.h>

#define NITER 1000
#define LRATE 0.1f

typedef unsigned int v2u __attribute__((ext_vector_type(2)));

__device__ __forceinline__ float rcpf(float x) { return __builtin_amdgcn_rcpf(x); }

__device__ __forceinline__ float readlane_f(float v, int l) {
    return __int_as_float(__builtin_amdgcn_readlane(__float_as_int(v), l));
}

template<int CTRL>
__device__ __forceinline__ float dpp_mov(float v) {
    return __int_as_float(__builtin_amdgcn_update_dpp(0, __float_as_int(v), CTRL, 0xF, 0xF, true));
}

__device__ __forceinline__ int lane_id() {
    return __builtin_amdgcn_mbcnt_hi(~0u, __builtin_amdgcn_mbcnt_lo(~0u, 0u));
}

__device__ __forceinline__ void swap16(float& x, float& y) {
#if __has_builtin(__builtin_amdgcn_permlane16_swap)
    v2u r = __builtin_amdgcn_permlane16_swap(__float_as_uint(x), __float_as_uint(y), false, false);
    x = __uint_as_float(r[0]);
    y = __uint_as_float(r[1]);
#else
    const bool up = lane_id() & 16;
    const float send = up ? x : y;
    const float recv = __shfl_xor(send, 16);
    x = up ? recv : x;
    y = up ? y : recv;
#endif
}

__device__ __forceinline__ void swap32(float& x, float& y) {
#if __has_builtin(__builtin_amdgcn_permlane32_swap)
    v2u r = __builtin_amdgcn_permlane32_swap(__float_as_uint(x), __float_as_uint(y), false, false);
    x = __uint_as_float(r[0]);
    y = __uint_as_float(r[1]);
#else
    const bool up = lane_id() & 32;
    const float send = up ? x : y;
    const float recv = __shfl_xor(send, 32);
    x = up ? recv : x;
    y = up ? y : recv;
#endif
}

// One block, 1024 threads = 16 waves (4/SIMD). Wave w owns section w (coefs
// wave-uniform). Lane L owns freqs 8L..8L+7 for forward/moments.
// Magnitude via cosine polynomial (R13, exact doubling fold); gradients via
// moment sums (verified absmax 0.0 since R9).
// PHASE-B (K-pass) VECTORIZED: thread t<128 owns freqs 4t..4t+3 and reads
// each wave-partial row as ONE ds_read_b128 -> 32 LDS wave-ops (vs 128 b32),
// cutting ~480 cyc/iter of exposed LDS-pipe time (the measured phase-model
// offset). Addr 4t+4*(t>>3) rotates banks +4 per 8 lanes: conflict-free.
__global__ __launch_bounds__(1024, 1)
void sgd_filter_design_kernel(const float* __restrict__ target,
                              const float* __restrict__ sos_init,
                              float* __restrict__ out)
{
    const int t = threadIdx.x;
    const int w = t >> 6;
    const int L = t & 63;

    __shared__ __align__(16) float wq[16][576];
    __shared__ __align__(16) float Kbuf[576];

    const float PI = 3.14159265358979323846f;
    float C1[8], C2[8];
    #pragma unroll
    for (int f = 0; f < 8; ++f) {
        const int n = 8 * L + f;
        const float wr = PI * (float)n / 511.0f;
        const float c1 = cosf(wr);
        C1[f] = c1;
        C2[f] = 2.0f * c1 * c1 - 1.0f;
    }

    // K-pass setup: thread t < 128 owns freqs 4t..4t+3
    float4 mKt4 = {0.f, 0.f, 0.f, 0.f};
    int kaddr4 = 0;
    if (t < 128) {
        const float4 tg = reinterpret_cast<const float4*>(target)[t];
        mKt4.x = -0.03392925639869154f * tg.x;
        mKt4.y = -0.03392925639869154f * tg.y;
        mKt4.z = -0.03392925639869154f * tg.z;
        mKt4.w = -0.03392925639869154f * tg.w;
        kaddr4 = 4 * t + 4 * (t >> 3);          // = base addr of freq 4t
    }

    const int sw = 8 * L + 4 * (L >> 2);        // 2-way = free
    const int col = ((L & 16) >> 2) | ((L & 32) >> 4) | (L & 1);
    const bool up1 = L & 1;

    float v0 = 0.0f;
    if (col < 6) v0 = sos_init[6 * w + col];
    float B0f = readlane_f(v0, 0);
    float B1f = readlane_f(v0, 1);
    float B2f = readlane_f(v0, 32);
    float A0f = readlane_f(v0, 33);
    float A1f = readlane_f(v0, 16);
    float A2f = readlane_f(v0, 17);

    for (int it = 0; it < NITER; ++it) {
        // ---- wave-uniform polynomial coefficients (x2 folded, exact) ----
        const float P0 = fmaf(B0f, B0f, fmaf(B1f, B1f, B2f * B2f));
        float P1 = B1f * (B0f + B2f); P1 += P1;
        float P2 = B0f * B2f;         P2 += P2;
        const float Q0 = fmaf(A0f, A0f, fmaf(A1f, A1f, A2f * A2f));
        float Q1 = A1f * (A0f + A2f); Q1 += Q1;
        float Q2 = A0f * A2f;         Q2 += Q2;

        // ---- forward: own section at 8 freqs ----
        float imn[8], qs[8];
        #pragma unroll
        for (int f = 0; f < 8; ++f) {
            float mn = fmaf(P2, C2[f], fmaf(P1, C1[f], P0));
            float md = fmaf(Q2, C2[f], fmaf(Q1, C1[f], Q0));
            mn = fmaxf(mn, 1e-18f);     // guard: poly can round negative
            md = fmaxf(md, 1e-18f);
            const float rr = rcpf(mn * md);
            imn[f] = rr * md;                              // 1/mn
            qs[f] = (rr * mn) * mn;                        // mn/md
        }
        {
            const float4 q0 = {qs[0], qs[1], qs[2], qs[3]};
            const float4 q1 = {qs[4], qs[5], qs[6], qs[7]};
            *reinterpret_cast<float4*>(&wq[w][sw])     = q0;
            *reinterpret_cast<float4*>(&wq[w][sw + 4]) = q1;
        }
        __syncthreads();   // b1: wq ready; fences last iter's Kbuf reads

        // ---- K-pass: 128 threads, 4 freqs each, b128 row reads ----
        if (t < 128) {
            float4 p0 = *reinterpret_cast<const float4*>(&wq[0][kaddr4]);
            float4 p1 = *reinterpret_cast<const float4*>(&wq[1][kaddr4]);
            float4 p2 = *reinterpret_cast<const float4*>(&wq[2][kaddr4]);
            float4 p3 = *reinterpret_cast<const float4*>(&wq[3][kaddr4]);
            #pragma unroll
            for (int ww = 4; ww < 16; ww += 4) {
                const float4 u0 = *reinterpret_cast<const float4*>(&wq[ww + 0][kaddr4]);
                const float4 u1 = *reinterpret_cast<const float4*>(&wq[ww + 1][kaddr4]);
                const float4 u2 = *reinterpret_cast<const float4*>(&wq[ww + 2][kaddr4]);
                const float4 u3 = *reinterpret_cast<const float4*>(&wq[ww + 3][kaddr4]);
                p0.x *= u0.x; p0.y *= u0.y; p0.z *= u0.z; p0.w *= u0.w;
                p1.x *= u1.x; p1.y *= u1.y; p1.z *= u1.z; p1.w *= u1.w;
                p2.x *= u2.x; p2.y *= u2.y; p2.z *= u2.z; p2.w *= u2.w;
                p3.x *= u3.x; p3.y *= u3.y; p3.z *= u3.z; p3.w *= u3.w;
            }
            p0.x *= p1.x; p0.y *= p1.y; p0.z *= p1.z; p0.w *= p1.w;
            p2.x *= p3.x; p2.y *= p3.y; p2.z *= p3.z; p2.w *= p3.w;
            p0.x *= p2.x; p0.y *= p2.y; p0.z *= p2.z; p0.w *= p2.w;
            float4 Kv;
            Kv.x = fmaf(__log2f(p0.x), 0.10213724040f, mKt4.x);
            Kv.y = fmaf(__log2f(p0.y), 0.10213724040f, mKt4.y);
            Kv.z = fmaf(__log2f(p0.z), 0.10213724040f, mKt4.z);
            Kv.w = fmaf(__log2f(p0.w), 0.10213724040f, mKt4.w);
            *reinterpret_cast<float4*>(&Kbuf[kaddr4]) = Kv;
        }
        __syncthreads();   // b2: Kbuf ready

        // ---- read K for own 8 freqs (swizzle-aligned b128 pair) ----
        const float4 k0 = *reinterpret_cast<const float4*>(&Kbuf[sw]);
        const float4 k1 = *reinterpret_cast<const float4*>(&Kbuf[sw + 4]);
        const float Kf[8] = {k0.x, k0.y, k0.z, k0.w, k1.x, k1.y, k1.z, k1.w};

        // ---- moment accumulation: 6 sums over own 8 freqs (F = E*qs) ----
        float X0, X1, X2, X3, X4, X5;
        #pragma unroll
        for (int f = 0; f < 8; ++f) {
            const float E = Kf[f] * imn[f];
            const float F = E * qs[f];                     // = K/md
            if (f == 0) {
                X0 = E;            X3 = F;
                X1 = E * C1[f];    X4 = F * C1[f];
                X2 = E * C2[f];    X5 = F * C2[f];
            } else {
                X0 += E;                      X3 += F;
                X1 = fmaf(E, C1[f], X1);      X4 = fmaf(F, C1[f], X4);
                X2 = fmaf(E, C2[f], X2);      X5 = fmaf(F, C2[f], X5);
            }
        }
        const float g6[6] = {X0, X1, X2, X3, X4, X5};

        // ---- butterfly reduce-scatter: 8 cols (6 real + 2 pad) ----
        float r4v[4];
        #pragma unroll
        for (int i = 0; i < 4; ++i) {            // mask 16, weight 4
            float x = g6[i];
            float y = (i + 4 < 6) ? g6[i + 4] : 0.0f;
            swap16(x, y);
            r4v[i] = x + y;
        }
        float r2v[2];
        #pragma unroll
        for (int i = 0; i < 2; ++i) {            // mask 32, weight 2
            float x = r4v[i], y = r4v[i + 2];
            swap32(x, y);
            r2v[i] = x + y;
        }
        float r1v;
        {                                         // mask 1 (DPP), weight 1
            const float x = r2v[0], y = r2v[1];
            const float P = up1 ? y : x, Q = up1 ? x : y;
            r1v = P + dpp_mov<0xB1>(Q);
        }
        r1v += dpp_mov<0x4E>(r1v);                // mask 2 full sum
        r1v += dpp_mov<0x128>(r1v);               // mask 8 full sum
        r1v += __shfl_xor(r1v, 4);                // mask 4 full sum

        // ---- extract the 6 moment sums (uniform), rebuild gradients ----
        const float S0 = readlane_f(r1v, 0);
        const float S1v = readlane_f(r1v, 1);
        const float S2v = readlane_f(r1v, 32);
        const float T0 = readlane_f(r1v, 33);
        const float T1v = readlane_f(r1v, 16);
        const float T2v = readlane_f(r1v, 17);

        const float gb0 = fmaf(B0f, S0, fmaf(B1f, S1v, B2f * S2v));
        const float gb1 = fmaf(B0f + B2f, S1v, B1f * S0);
        const float gb2 = fmaf(B0f, S2v, fmaf(B1f, S1v, B2f * S0));
        const float ga0 = fmaf(A0f, T0, fmaf(A1f, T1v, A2f * T2v));
        const float ga1 = fmaf(A0f + A2f, T1v, A1f * T0);
        const float ga2 = fmaf(A0f, T2v, fmaf(A1f, T1v, A2f * T0));

        B0f = fmaf(-LRATE, gb0, B0f);
        B1f = fmaf(-LRATE, gb1, B1f);
        B2f = fmaf(-LRATE, gb2, B2f);
        A0f = fmaf( LRATE, ga0, A0f);
        A1f = fmaf( LRATE, ga1, A1f);
        A2f = fmaf( LRATE, ga2, A2f);
    }

    if (L == 0) {
        out[6 * w + 0] = B0f;
        out[6 * w + 1] = B1f;
        out[6 * w + 2] = B2f;
        out[6 * w + 3] = A0f;
        out[6 * w + 4] = A1f;
        out[6 * w + 5] = A2f;
    }
}

extern "C" void kernel_launch(void* const* d_in, const int* in_sizes, int n_in,
                              void* d_out, int out_size, void* d_ws, size_t ws_size,
                              hipStream_t stream) {
    const float* target   = (const float*)d_in[0];   // (512,)
    const float* sos_init = (const float*)d_in[1];   // (1,16,6) = 96
    float* out = (float*)d_out;                      // 96 floats
    hipLaunchKernelGGL(sgd_filter_design_kernel, dim3(1), dim3(1024), 0, stream,
                       target, sos_init, out);
}

// Round 17
// 1594.267 us; speedup vs baseline: 3.8279x; 1.1664x over previous
//
#include <hip/hip_runtime.h>
#include <math.h>

#define NITER 1000
#define LRATE 0.1f

typedef unsigned int v2u __attribute__((ext_vector_type(2)));

__device__ __forceinline__ float rcpf(float x) { return __builtin_amdgcn_rcpf(x); }

__device__ __forceinline__ float readlane_f(float v, int l) {
    return __int_as_float(__builtin_amdgcn_readlane(__float_as_int(v), l));
}

template<int CTRL>
__device__ __forceinline__ float dpp_mov(float v) {
    return __int_as_float(__builtin_amdgcn_update_dpp(0, __float_as_int(v), CTRL, 0xF, 0xF, true));
}

__device__ __forceinline__ int lane_id() {
    return __builtin_amdgcn_mbcnt_hi(~0u, __builtin_amdgcn_mbcnt_lo(~0u, 0u));
}

__device__ __forceinline__ void swap16(float& x, float& y) {
#if __has_builtin(__builtin_amdgcn_permlane16_swap)
    v2u r = __builtin_amdgcn_permlane16_swap(__float_as_uint(x), __float_as_uint(y), false, false);
    x = __uint_as_float(r[0]);
    y = __uint_as_float(r[1]);
#else
    const bool up = lane_id() & 16;
    const float send = up ? x : y;
    const float recv = __shfl_xor(send, 16);
    x = up ? recv : x;
    y = up ? y : recv;
#endif
}

__device__ __forceinline__ void swap32(float& x, float& y) {
#if __has_builtin(__builtin_amdgcn_permlane32_swap)
    v2u r = __builtin_amdgcn_permlane32_swap(__float_as_uint(x), __float_as_uint(y), false, false);
    x = __uint_as_float(r[0]);
    y = __uint_as_float(r[1]);
#else
    const bool up = lane_id() & 32;
    const float send = up ? x : y;
    const float recv = __shfl_xor(send, 32);
    x = up ? recv : x;
    y = up ? y : recv;
#endif
}

// One block, 1024 threads = 16 waves (4/SIMD). Wave w owns section w (coefs
// wave-uniform). Lane L owns freqs 8L..8L+7 for forward/moments.
// Magnitude via cosine polynomial (exact doubling fold); gradients via moment
// sums (verified absmax 0.0 since R9); F = E*qs rebuild (R16-verified).
// PHASE-B K-pass: 256 threads, thread u owns freqs {2u,2u+1} which are
// ADJACENT in the R10 swizzled layout (a0 = 8(u>>2)+4(u>>4)+2(u&3), even) ->
// 16 ds_read_b64 per thread, 64 LDS wave-ops total (vs R10's 128 b32).
// Bank check per 16-lane phase: banks (2u+4(u>>4))%32 cover all 32 exactly
// once -> conflict-free (R16's pad-broken b128 lesson applied).
__global__ __launch_bounds__(1024, 1)
void sgd_filter_design_kernel(const float* __restrict__ target,
                              const float* __restrict__ sos_init,
                              float* __restrict__ out)
{
    const int t = threadIdx.x;
    const int w = t >> 6;
    const int L = t & 63;

    __shared__ __align__(16) float wq[16][576];
    __shared__ __align__(16) float Kbuf[576];

    const float PI = 3.14159265358979323846f;
    float C1[8], C2[8];
    #pragma unroll
    for (int f = 0; f < 8; ++f) {
        const int n = 8 * L + f;
        const float wr = PI * (float)n / 511.0f;
        const float c1 = cosf(wr);
        C1[f] = c1;
        C2[f] = 2.0f * c1 * c1 - 1.0f;
    }

    // K-pass setup: thread u < 256 owns freqs {2u, 2u+1} (LDS-adjacent)
    float2 mKt2 = {0.f, 0.f};
    int kaddr2 = 0;
    if (t < 256) {
        const float2 tg = reinterpret_cast<const float2*>(target)[t];
        mKt2.x = -0.03392925639869154f * tg.x;
        mKt2.y = -0.03392925639869154f * tg.y;
        kaddr2 = 8 * (t >> 2) + 4 * (t >> 4) + 2 * (t & 3);
    }

    const int sw = 8 * L + 4 * (L >> 2);        // 2-way = free (R10-verified)
    const int col = ((L & 16) >> 2) | ((L & 32) >> 4) | (L & 1);
    const bool up1 = L & 1;

    float v0 = 0.0f;
    if (col < 6) v0 = sos_init[6 * w + col];
    float B0f = readlane_f(v0, 0);
    float B1f = readlane_f(v0, 1);
    float B2f = readlane_f(v0, 32);
    float A0f = readlane_f(v0, 33);
    float A1f = readlane_f(v0, 16);
    float A2f = readlane_f(v0, 17);

    for (int it = 0; it < NITER; ++it) {
        // ---- wave-uniform polynomial coefficients (x2 folded, exact) ----
        const float P0 = fmaf(B0f, B0f, fmaf(B1f, B1f, B2f * B2f));
        float P1 = B1f * (B0f + B2f); P1 += P1;
        float P2 = B0f * B2f;         P2 += P2;
        const float Q0 = fmaf(A0f, A0f, fmaf(A1f, A1f, A2f * A2f));
        float Q1 = A1f * (A0f + A2f); Q1 += Q1;
        float Q2 = A0f * A2f;         Q2 += Q2;

        // ---- forward: own section at 8 freqs ----
        float imn[8], qs[8];
        #pragma unroll
        for (int f = 0; f < 8; ++f) {
            float mn = fmaf(P2, C2[f], fmaf(P1, C1[f], P0));
            float md = fmaf(Q2, C2[f], fmaf(Q1, C1[f], Q0));
            mn = fmaxf(mn, 1e-18f);     // guard: poly can round negative
            md = fmaxf(md, 1e-18f);
            const float rr = rcpf(mn * md);
            imn[f] = rr * md;                              // 1/mn
            qs[f] = (rr * mn) * mn;                        // mn/md
        }
        {
            const float4 q0 = {qs[0], qs[1], qs[2], qs[3]};
            const float4 q1 = {qs[4], qs[5], qs[6], qs[7]};
            *reinterpret_cast<float4*>(&wq[w][sw])     = q0;
            *reinterpret_cast<float4*>(&wq[w][sw + 4]) = q1;
        }
        __syncthreads();   // b1: wq ready; fences last iter's Kbuf reads

        // ---- K-pass: 256 threads, 2 freqs each, b64 reads ----
        if (t < 256) {
            float2 p0 = *reinterpret_cast<const float2*>(&wq[0][kaddr2]);
            float2 p1 = *reinterpret_cast<const float2*>(&wq[1][kaddr2]);
            float2 p2 = *reinterpret_cast<const float2*>(&wq[2][kaddr2]);
            float2 p3 = *reinterpret_cast<const float2*>(&wq[3][kaddr2]);
            #pragma unroll
            for (int ww = 4; ww < 16; ww += 4) {
                const float2 u0 = *reinterpret_cast<const float2*>(&wq[ww + 0][kaddr2]);
                const float2 u1 = *reinterpret_cast<const float2*>(&wq[ww + 1][kaddr2]);
                const float2 u2 = *reinterpret_cast<const float2*>(&wq[ww + 2][kaddr2]);
                const float2 u3 = *reinterpret_cast<const float2*>(&wq[ww + 3][kaddr2]);
                p0.x *= u0.x; p0.y *= u0.y;
                p1.x *= u1.x; p1.y *= u1.y;
                p2.x *= u2.x; p2.y *= u2.y;
                p3.x *= u3.x; p3.y *= u3.y;
            }
            p0.x *= p1.x; p0.y *= p1.y;
            p2.x *= p3.x; p2.y *= p3.y;
            p0.x *= p2.x; p0.y *= p2.y;
            float2 Kv;
            Kv.x = fmaf(__log2f(p0.x), 0.10213724040f, mKt2.x);
            Kv.y = fmaf(__log2f(p0.y), 0.10213724040f, mKt2.y);
            *reinterpret_cast<float2*>(&Kbuf[kaddr2]) = Kv;
        }
        __syncthreads();   // b2: Kbuf ready

        // ---- read K for own 8 freqs (swizzle-aligned b128 pair) ----
        const float4 k0 = *reinterpret_cast<const float4*>(&Kbuf[sw]);
        const float4 k1 = *reinterpret_cast<const float4*>(&Kbuf[sw + 4]);
        const float Kf[8] = {k0.x, k0.y, k0.z, k0.w, k1.x, k1.y, k1.z, k1.w};

        // ---- moment accumulation: 6 sums over own 8 freqs (F = E*qs) ----
        float X0, X1, X2, X3, X4, X5;
        #pragma unroll
        for (int f = 0; f < 8; ++f) {
            const float E = Kf[f] * imn[f];
            const float F = E * qs[f];                     // = K/md
            if (f == 0) {
                X0 = E;            X3 = F;
                X1 = E * C1[f];    X4 = F * C1[f];
                X2 = E * C2[f];    X5 = F * C2[f];
            } else {
                X0 += E;                      X3 += F;
                X1 = fmaf(E, C1[f], X1);      X4 = fmaf(F, C1[f], X4);
                X2 = fmaf(E, C2[f], X2);      X5 = fmaf(F, C2[f], X5);
            }
        }
        const float g6[6] = {X0, X1, X2, X3, X4, X5};

        // ---- butterfly reduce-scatter: 8 cols (6 real + 2 pad) ----
        float r4v[4];
        #pragma unroll
        for (int i = 0; i < 4; ++i) {            // mask 16, weight 4
            float x = g6[i];
            float y = (i + 4 < 6) ? g6[i + 4] : 0.0f;
            swap16(x, y);
            r4v[i] = x + y;
        }
        float r2v[2];
        #pragma unroll
        for (int i = 0; i < 2; ++i) {            // mask 32, weight 2
            float x = r4v[i], y = r4v[i + 2];
            swap32(x, y);
            r2v[i] = x + y;
        }
        float r1v;
        {                                         // mask 1 (DPP), weight 1
            const float x = r2v[0], y = r2v[1];
            const float P = up1 ? y : x, Q = up1 ? x : y;
            r1v = P + dpp_mov<0xB1>(Q);
        }
        r1v += dpp_mov<0x4E>(r1v);                // mask 2 full sum
        r1v += dpp_mov<0x128>(r1v);               // mask 8 full sum
        r1v += __shfl_xor(r1v, 4);                // mask 4 full sum

        // ---- extract the 6 moment sums (uniform), rebuild gradients ----
        const float S0 = readlane_f(r1v, 0);
        const float S1v = readlane_f(r1v, 1);
        const float S2v = readlane_f(r1v, 32);
        const float T0 = readlane_f(r1v, 33);
        const float T1v = readlane_f(r1v, 16);
        const float T2v = readlane_f(r1v, 17);

        const float gb0 = fmaf(B0f, S0, fmaf(B1f, S1v, B2f * S2v));
        const float gb1 = fmaf(B0f + B2f, S1v, B1f * S0);
        const float gb2 = fmaf(B0f, S2v, fmaf(B1f, S1v, B2f * S0));
        const float ga0 = fmaf(A0f, T0, fmaf(A1f, T1v, A2f * T2v));
        const float ga1 = fmaf(A0f + A2f, T1v, A1f * T0);
        const float ga2 = fmaf(A0f, T2v, fmaf(A1f, T1v, A2f * T0));

        B0f = fmaf(-LRATE, gb0, B0f);
        B1f = fmaf(-LRATE, gb1, B1f);
        B2f = fmaf(-LRATE, gb2, B2f);
        A0f = fmaf( LRATE, ga0, A0f);
        A1f = fmaf( LRATE, ga1, A1f);
        A2f = fmaf( LRATE, ga2, A2f);
    }

    if (L == 0) {
        out[6 * w + 0] = B0f;
        out[6 * w + 1] = B1f;
        out[6 * w + 2] = B2f;
        out[6 * w + 3] = A0f;
        out[6 * w + 4] = A1f;
        out[6 * w + 5] = A2f;
    }
}

extern "C" void kernel_launch(void* const* d_in, const int* in_sizes, int n_in,
                              void* d_out, int out_size, void* d_ws, size_t ws_size,
                              hipStream_t stream) {
    const float* target   = (const float*)d_in[0];   // (512,)
    const float* sos_init = (const float*)d_in[1];   // (1,16,6) = 96
    float* out = (float*)d_out;                      // 96 floats
    hipLaunchKernelGGL(sgd_filter_design_kernel, dim3(1), dim3(1024), 0, stream,
                       target, sos_init, out);
}

// Round 18
// 1479.722 us; speedup vs baseline: 4.1243x; 1.0774x over previous
//
#include <hip/hip_runtime.h>
#include <math.h>

#define NITER 1000
#define LRATE 0.1f

typedef unsigned int v2u __attribute__((ext_vector_type(2)));

__device__ __forceinline__ float rcpf(float x) { return __builtin_amdgcn_rcpf(x); }

__device__ __forceinline__ float readlane_f(float v, int l) {
    return __int_as_float(__builtin_amdgcn_readlane(__float_as_int(v), l));
}

template<int CTRL>
__device__ __forceinline__ float dpp_mov(float v) {
    return __int_as_float(__builtin_amdgcn_update_dpp(0, __float_as_int(v), CTRL, 0xF, 0xF, true));
}

__device__ __forceinline__ int lane_id() {
    return __builtin_amdgcn_mbcnt_hi(~0u, __builtin_amdgcn_mbcnt_lo(~0u, 0u));
}

__device__ __forceinline__ void swap16(float& x, float& y) {
#if __has_builtin(__builtin_amdgcn_permlane16_swap)
    v2u r = __builtin_amdgcn_permlane16_swap(__float_as_uint(x), __float_as_uint(y), false, false);
    x = __uint_as_float(r[0]);
    y = __uint_as_float(r[1]);
#else
    const bool up = lane_id() & 16;
    const float send = up ? x : y;
    const float recv = __shfl_xor(send, 16);
    x = up ? recv : x;
    y = up ? y : recv;
#endif
}

__device__ __forceinline__ void swap32(float& x, float& y) {
#if __has_builtin(__builtin_amdgcn_permlane32_swap)
    v2u r = __builtin_amdgcn_permlane32_swap(__float_as_uint(x), __float_as_uint(y), false, false);
    x = __uint_as_float(r[0]);
    y = __uint_as_float(r[1]);
#else
    const bool up = lane_id() & 32;
    const float send = up ? x : y;
    const float recv = __shfl_xor(send, 32);
    x = up ? recv : x;
    y = up ? y : recv;
#endif
}

// ============================================================================
// LOCKED-IN BEST (R10 configuration, measured 1478 us, absmax 0.0).
//
// Structure: one block, 1024 threads = 16 waves (4/SIMD). Wave w owns SOS
// section w; its 6 coefficients are wave-uniform register scalars. Lane L
// owns freqs 8L..8L+7. Per iteration:
//   A: forward (complex num/den, one fused rcp per freq) -> wq[w] (swizzled)
//   b1
//   B: K-pass on threads t<512 (freq t): 16 b32 reads, product tree, one
//      log2, write K to swizzled Kbuf
//   b2
//   C: Kf b128 reads, 6 moment sums, 8-col butterfly reduce-scatter
//      (permlane16/32_swap + DPP), readlane moment broadcast, closed-form
//      gradient rebuild, SGD update (all register-resident)
//
// Plateau evidence (R10-R17): 8 structural variants within [-0.3%,+29%] of
// this kernel; instruction cuts of 15-30% moved time <3%. Issue estimate
// ~1840 cyc/SIMD/iter vs measured 3547 cyc/iter: the residual is barrier +
// LDS round-trip latency, forced by (a) the algorithm's global section
// coupling per serial SGD step, (b) the 1024-thread block cap (max 16 waves
// of TLP on the single CU a serial loop can use). Not a chip roofline: the
// other 255 CUs are idle by problem structure.
// ============================================================================
__global__ __launch_bounds__(1024, 1)
void sgd_filter_design_kernel(const float* __restrict__ target,
                              const float* __restrict__ sos_init,
                              float* __restrict__ out)
{
    const int t = threadIdx.x;
    const int w = t >> 6;
    const int L = t & 63;

    __shared__ __align__(16) float wq[16][576];
    __shared__ __align__(16) float Kbuf[576];

    // per-freq constants (f32 scalar)
    const float PI = 3.14159265358979323846f;
    float C1[8], S1[8], C2[8], S2[8];
    #pragma unroll
    for (int f = 0; f < 8; ++f) {
        const int n = 8 * L + f;
        const float wr = PI * (float)n / 511.0f;
        const float c1 = cosf(wr), s1 = sinf(wr);
        C1[f] = c1; S1[f] = s1;
        C2[f] = 2.0f * c1 * c1 - 1.0f;
        S2[f] = 2.0f * s1 * c1;
    }

    float mKt = 0.0f;
    int kaddr = 0;
    if (t < 512) {
        mKt = -0.03392925639869154f * target[t];          // -ALPHA*tgt
        kaddr = 8 * (t >> 3) + 4 * (t >> 5) + (t & 7);    // swizzled
    }

    const int sw = 8 * L + 4 * (L >> 2);                  // 2-way = free
    const int col = ((L & 16) >> 2) | ((L & 32) >> 4) | (L & 1);
    const bool up1 = L & 1;

    // init coefficients as wave-uniform scalars
    float v0 = 0.0f;
    if (col < 6) v0 = sos_init[6 * w + col];
    float B0f = readlane_f(v0, 0);
    float B1f = readlane_f(v0, 1);
    float B2f = readlane_f(v0, 32);
    float A0f = readlane_f(v0, 33);
    float A1f = readlane_f(v0, 16);
    float A2f = readlane_f(v0, 17);

    for (int it = 0; it < NITER; ++it) {
        // ---- phase A: forward, own section at 8 freqs ----
        float imn[8], imd[8], qs[8];
        #pragma unroll
        for (int f = 0; f < 8; ++f) {
            const float nr = fmaf(B2f, C2[f], fmaf(B1f, C1[f], B0f));
            const float ni = fmaf(B2f, S2[f], B1f * S1[f]);   // = -Im(num)
            const float dr = fmaf(A2f, C2[f], fmaf(A1f, C1[f], A0f));
            const float di = fmaf(A2f, S2[f], A1f * S1[f]);   // = -Im(den)
            const float mn = fmaf(nr, nr, ni * ni);
            const float md = fmaf(dr, dr, di * di);
            const float rr = rcpf(mn * md);                    // one rcp
            const float iimd = rr * mn;                        // 1/md
            const float iimn = rr * md;                        // 1/mn
            qs[f] = mn * iimd;                                 // |num/den|^2
            imn[f] = iimn;
            imd[f] = iimd;
        }
        {
            const float4 q0 = {qs[0], qs[1], qs[2], qs[3]};
            const float4 q1 = {qs[4], qs[5], qs[6], qs[7]};
            *reinterpret_cast<float4*>(&wq[w][sw])     = q0;
            *reinterpret_cast<float4*>(&wq[w][sw + 4]) = q1;
        }
        __syncthreads();   // b1: wq ready; fences last iter's Kbuf reads

        // ---- phase B: K-pass, one freq per thread (waves 0-7) ----
        if (t < 512) {
            float p[16];
            #pragma unroll
            for (int ww = 0; ww < 16; ++ww) p[ww] = wq[ww][kaddr];
            p[0] *= p[8];  p[1] *= p[9];  p[2] *= p[10]; p[3] *= p[11];
            p[4] *= p[12]; p[5] *= p[13]; p[6] *= p[14]; p[7] *= p[15];
            p[0] *= p[4];  p[1] *= p[5];  p[2] *= p[6];  p[3] *= p[7];
            p[0] *= p[2];  p[1] *= p[3];
            p[0] *= p[1];
            // K = 0.102137240*log2(q) - ALPHA*tgt
            Kbuf[kaddr] = fmaf(__log2f(p[0]), 0.10213724040f, mKt);
        }
        __syncthreads();   // b2: Kbuf ready

        // ---- phase C: read K for own 8 freqs (swizzle-aligned b128s) ----
        const float4 k0 = *reinterpret_cast<const float4*>(&Kbuf[sw]);
        const float4 k1 = *reinterpret_cast<const float4*>(&Kbuf[sw + 4]);
        const float Kf[8] = {k0.x, k0.y, k0.z, k0.w, k1.x, k1.y, k1.z, k1.w};

        // moment accumulation: 6 sums over own 8 freqs
        float X0, X1, X2, X3, X4, X5;
        #pragma unroll
        for (int f = 0; f < 8; ++f) {
            const float E = Kf[f] * imn[f];
            const float F = Kf[f] * imd[f];
            if (f == 0) {
                X0 = E;            X3 = F;
                X1 = E * C1[f];    X4 = F * C1[f];
                X2 = E * C2[f];    X5 = F * C2[f];
            } else {
                X0 += E;                      X3 += F;
                X1 = fmaf(E, C1[f], X1);      X4 = fmaf(F, C1[f], X4);
                X2 = fmaf(E, C2[f], X2);      X5 = fmaf(F, C2[f], X5);
            }
        }
        const float g6[6] = {X0, X1, X2, X3, X4, X5};

        // butterfly reduce-scatter: 8 cols (6 real + 2 pad)
        float r4v[4];
        #pragma unroll
        for (int i = 0; i < 4; ++i) {            // mask 16, weight 4
            float x = g6[i];
            float y = (i + 4 < 6) ? g6[i + 4] : 0.0f;
            swap16(x, y);
            r4v[i] = x + y;
        }
        float r2v[2];
        #pragma unroll
        for (int i = 0; i < 2; ++i) {            // mask 32, weight 2
            float x = r4v[i], y = r4v[i + 2];
            swap32(x, y);
            r2v[i] = x + y;
        }
        float r1v;
        {                                         // mask 1 (DPP), weight 1
            const float x = r2v[0], y = r2v[1];
            const float P = up1 ? y : x, Q = up1 ? x : y;
            r1v = P + dpp_mov<0xB1>(Q);
        }
        r1v += dpp_mov<0x4E>(r1v);                // mask 2 full sum
        r1v += dpp_mov<0x128>(r1v);               // mask 8 full sum
        r1v += __shfl_xor(r1v, 4);                // mask 4 full sum

        // extract the 6 moment sums (wave-uniform), rebuild all gradients
        const float S0 = readlane_f(r1v, 0);      // sum E
        const float S1v = readlane_f(r1v, 1);     // sum E*C1
        const float S2v = readlane_f(r1v, 32);    // sum E*C2
        const float T0 = readlane_f(r1v, 33);     // sum F
        const float T1v = readlane_f(r1v, 16);    // sum F*C1
        const float T2v = readlane_f(r1v, 17);    // sum F*C2

        const float gb0 = fmaf(B0f, S0, fmaf(B1f, S1v, B2f * S2v));
        const float gb1 = fmaf(B0f + B2f, S1v, B1f * S0);
        const float gb2 = fmaf(B0f, S2v, fmaf(B1f, S1v, B2f * S0));
        const float ga0 = fmaf(A0f, T0, fmaf(A1f, T1v, A2f * T2v));
        const float ga1 = fmaf(A0f + A2f, T1v, A1f * T0);
        const float ga2 = fmaf(A0f, T2v, fmaf(A1f, T1v, A2f * T0));

        // b-side: true grad = +g -> minus; a-side: true grad = -g -> plus
        B0f = fmaf(-LRATE, gb0, B0f);
        B1f = fmaf(-LRATE, gb1, B1f);
        B2f = fmaf(-LRATE, gb2, B2f);
        A0f = fmaf( LRATE, ga0, A0f);
        A1f = fmaf( LRATE, ga1, A1f);
        A2f = fmaf( LRATE, ga2, A2f);
    }

    if (L == 0) {
        out[6 * w + 0] = B0f;
        out[6 * w + 1] = B1f;
        out[6 * w + 2] = B2f;
        out[6 * w + 3] = A0f;
        out[6 * w + 4] = A1f;
        out[6 * w + 5] = A2f;
    }
}

extern "C" void kernel_launch(void* const* d_in, const int* in_sizes, int n_in,
                              void* d_out, int out_size, void* d_ws, size_t ws_size,
                              hipStream_t stream) {
    const float* target   = (const float*)d_in[0];   // (512,)
    const float* sos_init = (const float*)d_in[1];   // (1,16,6) = 96
    float* out = (float*)d_out;                      // 96 floats
    hipLaunchKernelGGL(sgd_filter_design_kernel, dim3(1), dim3(1024), 0, stream,
                       target, sos_init, out);
}